// Round 9
// baseline (1707.115 us; speedup 1.0000x reference)
//
#include <hip/hip_runtime.h>
#include <hip/hip_bf16.h>
#include <cstdint>

#define HDIM 128
#define GRID 512
#define MAGIC 0x13572468u

typedef __bf16 bf16x8 __attribute__((ext_vector_type(8)));
typedef unsigned short usx8 __attribute__((ext_vector_type(8)));
typedef float fx4 __attribute__((ext_vector_type(4)));

__device__ __forceinline__ float bf2f(unsigned short u) {
    unsigned int x = ((unsigned int)u) << 16;
    return __uint_as_float(x);
}
__device__ __forceinline__ unsigned short f2bf(float f) {
    unsigned int x = __float_as_uint(f);
    x += 0x7fffu + ((x >> 16) & 1u);
    return (unsigned short)(x >> 16);
}

__device__ __forceinline__ void detect_local(const unsigned int* xw, const unsigned int* eiw,
                                             int& f0, int& f1) {
    int sane = 0;
    for (int k = 0; k < 64; k++) {
        unsigned int w = xw[k];
        unsigned short ss[2] = {(unsigned short)(w & 0xffffu), (unsigned short)(w >> 16)};
        for (int q = 0; q < 2; q++) {
            int e = (ss[q] >> 7) & 0xFF;
            if ((ss[q] & 0x7fffu) == 0 || (e >= 100 && e <= 140)) sane++;
        }
    }
    f0 = (sane >= 110) ? 1 : 0;
    int zeros = 0;
    for (int k = 1; k < 64; k += 2)
        if (eiw[k] == 0) zeros++;
    f1 = (zeros >= 24) ? 1 : 0;
}

// software grid barrier: 8 spread sub-counters -> master -> flag (per-barrier 256 uints)
__device__ __forceinline__ void gbar(unsigned int* bar, int id) {
    __syncthreads();
    if (threadIdx.x == 0) {
        unsigned int* B = bar + id * 256;
        int j = blockIdx.x & 7;
        unsigned int old =
            __hip_atomic_fetch_add(&B[j * 16], 1u, __ATOMIC_ACQ_REL, __HIP_MEMORY_SCOPE_AGENT);
        bool released = false;
        if (old == (GRID / 8 - 1)) {
            unsigned int m =
                __hip_atomic_fetch_add(&B[128], 1u, __ATOMIC_ACQ_REL, __HIP_MEMORY_SCOPE_AGENT);
            if (m == 7u) {
                __hip_atomic_store(&B[144], 1u, __ATOMIC_RELEASE, __HIP_MEMORY_SCOPE_AGENT);
                released = true;
            }
        }
        if (!released) {
            while (__hip_atomic_load(&B[144], __ATOMIC_ACQUIRE, __HIP_MEMORY_SCOPE_AGENT) == 0u) {
                __builtin_amdgcn_s_sleep(16);
            }
        }
    }
    __syncthreads();
}

struct ParamTab {
    const void* p[15];
    int n[15];
    int off[15];
};

struct MegaParams {
    const void* x;
    const void* ei;
    const void* batch;
    const void* W1;
    const void* W2;
    const void* W3;
    ParamTab tab;
    unsigned int* bar;
    float* gsumAll;
    int* Ct;
    int* btot;
    int* goff;
    int* gcnt;
    int* csrc;
    int* offs;
    int* cnt;
    float* dis;
    unsigned int* pairs;
    unsigned short* wconv;
    unsigned short* wfrag;
    unsigned short* hw;
    unsigned short* aggbuf;
    float* pooled;
    float* psc;
    float* psh;
    void* out;
    int E, N, G, NB, ntiles, TILE;
    float invn;
};

#define oB 49152

__global__ __launch_bounds__(256, 2) void mega(MegaParams P) {
    __shared__ __align__(16) unsigned char smem[18688];
    __shared__ int lfs[2];
    const int b = blockIdx.x, t = threadIdx.x;
    unsigned int* bar = P.bar;

    // ---- barrier init: block 0 zeroes state, releases magic; all wait on magic ----
    if (b == 0) {
        for (int i = t; i < 4096; i += 256)
            __hip_atomic_store(&bar[i], 0u, __ATOMIC_RELAXED, __HIP_MEMORY_SCOPE_AGENT);
        __syncthreads();
        if (t == 0)
            __hip_atomic_store(&bar[4096], MAGIC, __ATOMIC_RELEASE, __HIP_MEMORY_SCOPE_AGENT);
    }
    if (t == 0) {
        int a0, a1;
        detect_local((const unsigned int*)P.x, (const unsigned int*)P.ei, a0, a1);
        lfs[0] = a0;
        lfs[1] = a1;
        while (__hip_atomic_load(&bar[4096], __ATOMIC_ACQUIRE, __HIP_MEMORY_SCOPE_AGENT) != MAGIC) {
            __builtin_amdgcn_s_sleep(16);
        }
    }
    __syncthreads();
    const int lf0 = lfs[0], lf1 = lfs[1];
    const int* ei32 = (const int*)P.ei;

    // ======== P0: hist | param-convert | gbounds | repack | zero ========
    if (b < P.ntiles) {
        int* h = (int*)smem;
        for (int i = t; i < P.NB; i += 256) h[i] = 0;
        __syncthreads();
        int base = b * P.TILE;
        for (int i = t; i < P.TILE; i += 256) {
            int idx = base + i;
            if (idx < P.E) {
                int d = lf1 ? ei32[2 * ((size_t)P.E + idx)] : ei32[(size_t)P.E + idx];
                atomicAdd(&h[d >> 9], 1);
            }
        }
        __syncthreads();
        for (int k = t; k < P.NB; k += 256) P.Ct[k * P.ntiles + b] = h[k];
    } else if (b < P.ntiles + 15) {
        int pb = b - P.ntiles;
        const void* src = P.tab.p[pb];
        int n = P.tab.n[pb];
        unsigned short* o = P.wconv + P.tab.off[pb];
        if (lf0) {
            const unsigned short* s = (const unsigned short*)src;
            for (int i = t; i < n; i += 256) o[i] = s[i];
        } else {
            const float* s = (const float*)src;
            for (int i = t; i < n; i += 256) o[i] = f2bf(s[i]);
        }
    } else if (b < P.ntiles + 17) {
        int gi = (b - P.ntiles - 15) * 256 + t;
        if (gi < P.G) {
            auto getb = [&](int i) -> int {
                return lf1 ? (int)((const long long*)P.batch)[i] : ((const int*)P.batch)[i];
            };
            auto lower = [&](int val) -> int {
                int lo = 0, hi = P.N;
                while (lo < hi) {
                    int mid = (lo + hi) >> 1;
                    if (getb(mid) < val) lo = mid + 1;
                    else hi = mid;
                }
                return lo;
            };
            int lo = lower(gi), hi = lower(gi + 1);
            P.goff[gi] = lo;
            P.gcnt[gi] = hi - lo;
        }
    } else if (b < P.ntiles + 41) {
        int idx = (b - P.ntiles - 17) * 256 + t;  // 0..6143
        int layer = idx >> 11;
        int rem = idx & 2047;
        int kt = rem >> 9, nt = (rem >> 6) & 7, lane = rem & 63;
        const void* W = (layer == 0) ? P.W1 : ((layer == 1) ? P.W2 : P.W3);
        int row = lane & 15, quad = lane >> 4;
        unsigned short* o =
            P.wfrag + ((size_t)layer * 2048 + (size_t)((kt * 8 + nt) * 64 + lane)) * 8;
#pragma unroll
        for (int j = 0; j < 8; j++) {
            int k = kt * 32 + quad * 8 + j;
            int off = k * HDIM + nt * 16 + row;
            o[j] = lf0 ? ((const unsigned short*)W)[off] : f2bf(((const float*)W)[off]);
        }
    } else if (b == P.ntiles + 41) {
        for (int i = t; i < 6144; i += 256) P.gsumAll[i] = 0.f;
    }
    gbar(bar, 0);

    // ======== P1: per-bucket exclusive scan of Ct over tiles (ntiles<=512) ========
    if (b < P.NB) {
        int* buf = (int*)smem;
        int base = b * P.ntiles;
        int v0 = (2 * t < P.ntiles) ? P.Ct[base + 2 * t] : 0;
        int v1 = (2 * t + 1 < P.ntiles) ? P.Ct[base + 2 * t + 1] : 0;
        int s = v0 + v1;
        buf[t] = s;
        __syncthreads();
        for (int o = 1; o < 256; o <<= 1) {
            int a = (t >= o) ? buf[t - o] : 0;
            __syncthreads();
            buf[t] += a;
            __syncthreads();
        }
        int excl = buf[t] - s;
        if (2 * t < P.ntiles) P.Ct[base + 2 * t] = excl;
        if (2 * t + 1 < P.ntiles) P.Ct[base + 2 * t + 1] = excl + v0;
        if (t == 255) P.btot[b] = buf[255];
    }
    gbar(bar, 1);

    // ======== P2: scatter to bucket-contiguous packed pairs ========
    if (b < P.ntiles) {
        int* cur = (int*)smem;          // 1024 ints
        int* bb = (int*)(smem + 4096);  // 256 ints
        int v = (t < P.NB) ? P.btot[t] : 0;
        bb[t] = v;
        __syncthreads();
        for (int o = 1; o < 256; o <<= 1) {
            int a = (t >= o) ? bb[t - o] : 0;
            __syncthreads();
            bb[t] += a;
            __syncthreads();
        }
        if (t < P.NB) cur[t] = (bb[t] - v) + P.Ct[t * P.ntiles + b];
        __syncthreads();
        int base = b * P.TILE;
        for (int i = t; i < P.TILE; i += 256) {
            int idx = base + i;
            if (idx < P.E) {
                int s, d;
                if (lf1) {
                    s = ei32[2 * (size_t)idx];
                    d = ei32[2 * ((size_t)P.E + idx)];
                } else {
                    s = ei32[idx];
                    d = ei32[(size_t)P.E + idx];
                }
                int pos = atomicAdd(&cur[d >> 9], 1);
                P.pairs[pos] = ((unsigned)(d & 511) << 23) | (unsigned)s;
            }
        }
    }
    gbar(bar, 2);

    // ======== P3: per-bucket group-by-node -> csrc/offs/cnt/dis ========
    if (b < P.NB) {
        int* hist = (int*)smem;            // 512
        int* start = (int*)(smem + 2048);  // 512
        int* cur = (int*)(smem + 4096);    // 512
        int* ps = (int*)(smem + 6144);     // 256
        int* bb = (int*)(smem + 7168);     // 256
        int node0 = b * 512;
        int v = (t < P.NB) ? P.btot[t] : 0;
        bb[t] = v;
        __syncthreads();
        for (int o = 1; o < 256; o <<= 1) {
            int a = (t >= o) ? bb[t - o] : 0;
            __syncthreads();
            bb[t] += a;
            __syncthreads();
        }
        int lo = bb[b] - P.btot[b];
        int hi = lo + P.btot[b];
        for (int i = t; i < 512; i += 256) hist[i] = 0;
        __syncthreads();
        for (int i = lo + t; i < hi; i += 256) atomicAdd(&hist[P.pairs[i] >> 23], 1);
        __syncthreads();
        ps[t] = hist[2 * t] + hist[2 * t + 1];
        __syncthreads();
        for (int o = 1; o < 256; o <<= 1) {
            int a = (t >= o) ? ps[t - o] : 0;
            __syncthreads();
            ps[t] += a;
            __syncthreads();
        }
        int e = t ? ps[t - 1] : 0;
        start[2 * t] = e;
        start[2 * t + 1] = e + hist[2 * t];
        __syncthreads();
        for (int i = t; i < 512; i += 256) {
            cur[i] = 0;
            int node = node0 + i;
            if (node < P.N) {
                P.offs[node] = lo + start[i];
                P.cnt[node] = hist[i];
                P.dis[node] = rsqrtf((float)(hist[i] + 1));
            }
        }
        __syncthreads();
        for (int i = lo + t; i < hi; i += 256) {
            unsigned int p = P.pairs[i];
            int l = p >> 23;
            int pos = lo + start[l] + atomicAdd(&cur[l], 1);
            P.csrc[pos] = (int)(p & 0x7fffffu);
        }
    }
    gbar(bar, 3);

    // ======== layers: mm -> aggregate ========
    for (int l = 0; l < 3; l++) {
        // ---- mm: hw[m,:] = dis[m] * (bnrelu(A)[m,:] @ W) ----
        {
            float* scs = (float*)smem;                              // 128 f
            float* shs = (float*)(smem + 512);                      // 128 f
            unsigned short* ldsC = (unsigned short*)(smem + 1024);  // 4*16*136 us
            if (l && t < 128) {
                const float* gp = P.gsumAll + (size_t)(l - 1) * 2048;
                float s = 0.f, s2 = 0.f;
#pragma unroll
                for (int r = 0; r < 8; r++) {
                    s += gp[r * 256 + t];
                    s2 += gp[r * 256 + 128 + t];
                }
                const unsigned short* gam = P.wconv + oB + (l - 1) * 384 + 128;
                const unsigned short* bet = P.wconv + oB + (l - 1) * 384 + 256;
                float m = s * P.invn;
                float vv = s2 * P.invn - m * m;
                float sc = bf2f(gam[t]) * rsqrtf(vv + 1e-5f);
                scs[t] = sc;
                shs[t] = bf2f(bet[t]) - m * sc;
            }
            __syncthreads();
            const unsigned short* Wf = P.wfrag + (size_t)l * HDIM * HDIM;
            int lane = t & 63, wv = t >> 6;
            int row = lane & 15, quad = lane >> 4;
            bool xfp32 = (l == 0) && !lf0;
            const unsigned short* Abase = (l == 0) ? (const unsigned short*)P.x : P.aggbuf;
            int nmt = (P.N + 15) >> 4;
            for (int tile = b * 4 + wv; tile < nmt; tile += GRID * 4) {
                int m0 = tile * 16;
                const unsigned short* arow = Abase + (size_t)(m0 + row) * HDIM + quad * 8;
                const float* arowf = (const float*)P.x + (size_t)(m0 + row) * HDIM + quad * 8;
                fx4 acc[8];
#pragma unroll
                for (int k = 0; k < 8; k++) acc[k] = (fx4){0.f, 0.f, 0.f, 0.f};
#pragma unroll
                for (int kt = 0; kt < 4; kt++) {
                    bf16x8 a;
                    if (xfp32) {
                        fx4 f0 = *(const fx4*)(arowf + kt * 32);
                        fx4 f1 = *(const fx4*)(arowf + kt * 32 + 4);
                        usx8 tt;
#pragma unroll
                        for (int q = 0; q < 4; q++) tt[q] = f2bf(f0[q]);
#pragma unroll
                        for (int q = 0; q < 4; q++) tt[4 + q] = f2bf(f1[q]);
                        a = __builtin_bit_cast(bf16x8, tt);
                    } else {
                        usx8 raw = *(const usx8*)(arow + kt * 32);
                        if (l) {
                            int col = kt * 32 + quad * 8;
                            fx4 s0 = *(const fx4*)&scs[col];
                            fx4 s1 = *(const fx4*)&scs[col + 4];
                            fx4 h0 = *(const fx4*)&shs[col];
                            fx4 h1 = *(const fx4*)&shs[col + 4];
                            usx8 tt;
#pragma unroll
                            for (int q = 0; q < 4; q++)
                                tt[q] = f2bf(fmaxf(s0[q] * bf2f(raw[q]) + h0[q], 0.f));
#pragma unroll
                            for (int q = 0; q < 4; q++)
                                tt[4 + q] = f2bf(fmaxf(s1[q] * bf2f(raw[4 + q]) + h1[q], 0.f));
                            a = __builtin_bit_cast(bf16x8, tt);
                        } else {
                            a = __builtin_bit_cast(bf16x8, raw);
                        }
                    }
                    const unsigned short* wf = Wf + ((size_t)(kt * 8) * 64 + lane) * 8;
#pragma unroll
                    for (int nt = 0; nt < 8; nt++) {
                        bf16x8 bfr =
                            __builtin_bit_cast(bf16x8, *(const usx8*)(wf + (size_t)nt * 64 * 8));
                        acc[nt] =
                            __builtin_amdgcn_mfma_f32_16x16x32_bf16(a, bfr, acc[nt], 0, 0, 0);
                    }
                }
                float dsc[4];
#pragma unroll
                for (int r = 0; r < 4; r++) dsc[r] = P.dis[m0 + quad * 4 + r];
                unsigned short* lw = ldsC + wv * 16 * 136;
#pragma unroll
                for (int nt = 0; nt < 8; nt++) {
                    int col = nt * 16 + row;
#pragma unroll
                    for (int r = 0; r < 4; r++) {
                        lw[(quad * 4 + r) * 136 + col] = f2bf(acc[nt][r] * dsc[r]);
                    }
                }
                int row16 = lane >> 2;
                int seg = lane & 3;
                const unsigned short* src = lw + row16 * 136 + seg * 32;
                unsigned short* dst = P.hw + (size_t)(m0 + row16) * HDIM + seg * 32;
#pragma unroll
                for (int k = 0; k < 4; k++) {
                    *(usx8*)(dst + k * 8) = *(const usx8*)(src + k * 8);
                }
            }
        }
        gbar(bar, 4 + 2 * l);

        // ---- aggregate + fused BN stats ----
        {
            float* red = (float*)smem;  // 16*128 f = 8KB
            int lane = t & 63, wv = t >> 6;
            int grp = lane >> 4, sub = lane & 15;
            int colb = sub * 8;
            const unsigned short* bias = P.wconv + oB + l * 384;
            usx8 bv = *(const usx8*)(bias + colb);
            float csum[8], csq[8];
#pragma unroll
            for (int q = 0; q < 8; q++) {
                csum[q] = 0.f;
                csq[q] = 0.f;
            }
            int stride = GRID * 16;
            for (int node = b * 16 + wv * 4 + grp; node < P.N; node += stride) {
                usx8 sv = *(const usx8*)(P.hw + (size_t)node * HDIM + colb);
                float a[8];
#pragma unroll
                for (int q = 0; q < 8; q++) a[q] = bf2f(sv[q]);
                int o = P.offs[node], c = P.cnt[node];
                int s0 = (c > 0) ? P.csrc[o] : 0;
                int s1 = (c > 1) ? P.csrc[o + 1] : 0;
                int s2 = (c > 2) ? P.csrc[o + 2] : 0;
                int s3 = (c > 3) ? P.csrc[o + 3] : 0;
                int j = 0;
                while (j < c) {
                    usx8 v0 = *(const usx8*)(P.hw + (size_t)s0 * HDIM + colb);
                    usx8 v1 = *(const usx8*)(P.hw + (size_t)s1 * HDIM + colb);
                    usx8 v2 = *(const usx8*)(P.hw + (size_t)s2 * HDIM + colb);
                    usx8 v3 = *(const usx8*)(P.hw + (size_t)s3 * HDIM + colb);
                    s0 = (j + 4 < c) ? P.csrc[o + j + 4] : 0;
                    s1 = (j + 5 < c) ? P.csrc[o + j + 5] : 0;
                    s2 = (j + 6 < c) ? P.csrc[o + j + 6] : 0;
                    s3 = (j + 7 < c) ? P.csrc[o + j + 7] : 0;
#pragma unroll
                    for (int q = 0; q < 8; q++) a[q] += bf2f(v0[q]);
                    if (j + 1 < c) {
#pragma unroll
                        for (int q = 0; q < 8; q++) a[q] += bf2f(v1[q]);
                    }
                    if (j + 2 < c) {
#pragma unroll
                        for (int q = 0; q < 8; q++) a[q] += bf2f(v2[q]);
                    }
                    if (j + 3 < c) {
#pragma unroll
                        for (int q = 0; q < 8; q++) a[q] += bf2f(v3[q]);
                    }
                    j += 4;
                }
                float di = P.dis[node];
                usx8 ov;
#pragma unroll
                for (int q = 0; q < 8; q++) {
                    float val = bf2f(bv[q]) + di * a[q];
                    ov[q] = f2bf(val);
                    float vr = bf2f(ov[q]);
                    csum[q] += vr;
                    csq[q] += vr * vr;
                }
                *(usx8*)(P.aggbuf + (size_t)node * HDIM + colb) = ov;
            }
            float* gsum8 = P.gsumAll + (size_t)l * 2048;
            int gidx = wv * 4 + grp;
            int rep = (b & 7) * 256;
            __syncthreads();
#pragma unroll
            for (int q = 0; q < 8; q++) red[gidx * 128 + colb + q] = csum[q];
            __syncthreads();
            if (t < 128) {
                float s = 0.f;
#pragma unroll
                for (int g = 0; g < 16; g++) s += red[g * 128 + t];
                atomicAdd(&gsum8[rep + t], s);
            }
            __syncthreads();
#pragma unroll
            for (int q = 0; q < 8; q++) red[gidx * 128 + colb + q] = csq[q];
            __syncthreads();
            if (t < 128) {
                float s = 0.f;
#pragma unroll
                for (int g = 0; g < 16; g++) s += red[g * 128 + t];
                atomicAdd(&gsum8[rep + 128 + t], s);
            }
        }
        gbar(bar, 5 + 2 * l);
    }

    // ======== pool (BN3+ReLU fused) ========
    {
        float* scs = (float*)smem;
        float* shs = (float*)(smem + 512);
        float* ls = (float*)(smem + 1024);
        if (t < 128) {
            const float* gp = P.gsumAll + 2 * 2048;
            float s = 0.f, s2 = 0.f;
#pragma unroll
            for (int r = 0; r < 8; r++) {
                s += gp[r * 256 + t];
                s2 += gp[r * 256 + 128 + t];
            }
            const unsigned short* gam = P.wconv + oB + 2 * 384 + 128;
            const unsigned short* bet = P.wconv + oB + 2 * 384 + 256;
            float m = s * P.invn;
            float vv = s2 * P.invn - m * m;
            float sc = bf2f(gam[t]) * rsqrtf(vv + 1e-5f);
            scs[t] = sc;
            shs[t] = bf2f(bet[t]) - m * sc;
        }
        __syncthreads();
        for (int g = b; g < P.G; g += GRID) {
            int c = t & 127, pp = t >> 7;
            float scale = scs[c], shift = shs[c];
            int s = P.goff[g], cn = P.gcnt[g];
            float acc = 0.f;
            for (int r = s + pp; r < s + cn; r += 2)
                acc += fmaxf(scale * bf2f(P.aggbuf[(size_t)r * HDIM + c]) + shift, 0.f);
            ls[t] = acc;
            __syncthreads();
            if (t < 128)
                P.pooled[(size_t)g * HDIM + t] = (ls[t] + ls[t + 128]) / fmaxf((float)cn, 1.f);
            __syncthreads();
        }
    }
    gbar(bar, 10);

    // ======== pooled BN (block 0) ========
    if (b == 0) {
        float* ls = (float*)smem;
        float* ls2 = (float*)(smem + 1024);
        int c = t & 127, pp = t >> 7;
        float s = 0.f, s2 = 0.f;
        for (int r = pp; r < P.G; r += 2) {
            float v = P.pooled[(size_t)r * HDIM + c];
            s += v;
            s2 += v * v;
        }
        ls[t] = s;
        ls2[t] = s2;
        __syncthreads();
        if (t < 128) {
            float S = ls[t] + ls[t + 128];
            float S2 = ls2[t] + ls2[t + 128];
            float m = S / (float)P.G;
            float v = S2 / (float)P.G - m * m;
            const unsigned short* gp = P.wconv + oB + 1152;
            const unsigned short* bep = P.wconv + oB + 1280;
            float sc = bf2f(gp[t]) * rsqrtf(v + 1e-5f);
            P.psc[t] = sc;
            P.psh[t] = bf2f(bep[t]) - m * sc;
        }
    }
    gbar(bar, 11);

    // ======== MLP head + log_softmax ========
    {
        const int oLB1 = oB + 1408;
        const int oLW1 = oLB1 + 128;
        const int oLW2 = oLW1 + 16384;
        const int oLB2 = oLW2 + 1280;
        float* row = (float*)smem;          // 128
        float* z1s = (float*)(smem + 512);  // 128
        float* z2 = (float*)(smem + 1024);  // 16
        float* lsep = (float*)(smem + 1088);
        for (int g = b; g < P.G; g += GRID) {
            if (t < 128) row[t] = P.psc[t] * P.pooled[(size_t)g * HDIM + t] + P.psh[t];
            __syncthreads();
            if (t < 128) {
                const unsigned short* lw1 = P.wconv + oLW1;
                float acc = bf2f(P.wconv[oLB1 + t]);
                for (int k = 0; k < 128; k++) acc += row[k] * bf2f(lw1[k * HDIM + t]);
                z1s[t] = fmaxf(acc, 0.f);
            }
            __syncthreads();
            if (t < 10) {
                const unsigned short* lw2 = P.wconv + oLW2;
                float a = bf2f(P.wconv[oLB2 + t]);
                for (int k = 0; k < 128; k++) a += z1s[k] * bf2f(lw2[k * 10 + t]);
                z2[t] = a;
            }
            __syncthreads();
            if (t == 0) {
                float m = z2[0];
                for (int j = 1; j < 10; j++) m = fmaxf(m, z2[j]);
                float s = 0.f;
                for (int j = 0; j < 10; j++) s += expf(z2[j] - m);
                *lsep = m + logf(s);
            }
            __syncthreads();
            if (t < 10) {
                float v = z2[t] - *lsep;
                if (lf0) ((unsigned short*)P.out)[g * 10 + t] = f2bf(v);
                else ((float*)P.out)[g * 10 + t] = v;
            }
            __syncthreads();
        }
    }
}

extern "C" void kernel_launch(void* const* d_in, const int* in_sizes, int n_in,
                              void* d_out, int out_size, void* d_ws, size_t ws_size,
                              hipStream_t stream) {
    int N_ = in_sizes[2];
    int E_ = in_sizes[1] / 2;
    int G_ = out_size / 10;

    int TILE = 4096;
    while ((E_ + TILE - 1) / TILE + 42 > GRID) TILE *= 2;  // roles must fit in grid
    int NB = (N_ + 511) / 512;  // <= 256 required by in-kernel base scans
    int ntiles = (E_ + TILE - 1) / TILE;
    int L = NB * ntiles;

    char* ws = (char*)d_ws;
    auto alloc = [&](size_t bytes) -> char* {
        char* p = ws;
        ws += (bytes + 255) & ~(size_t)255;
        return p;
    };
    MegaParams P;
    P.bar = (unsigned int*)alloc(4200 * 4);
    P.x = d_in[0];
    P.ei = d_in[1];
    P.batch = d_in[2];
    P.W1 = d_in[3];
    P.W2 = d_in[7];
    P.W3 = d_in[11];
    P.dis = (float*)alloc((size_t)N_ * 4);
    P.offs = (int*)alloc((size_t)N_ * 4);
    P.cnt = (int*)alloc((size_t)N_ * 4);
    P.Ct = (int*)alloc((size_t)L * 4);
    P.btot = (int*)alloc(1024);
    P.pairs = (unsigned int*)alloc((size_t)E_ * 4);
    P.csrc = (int*)alloc((size_t)E_ * 4);
    P.hw = (unsigned short*)alloc((size_t)N_ * HDIM * 2);
    P.aggbuf = (unsigned short*)alloc((size_t)N_ * HDIM * 2);
    P.wconv = (unsigned short*)alloc(70000 * 2);
    P.wfrag = (unsigned short*)alloc(3 * HDIM * HDIM * 2);
    P.gsumAll = (float*)alloc(6144 * 4);
    P.gcnt = (int*)alloc((size_t)G_ * 4);
    P.goff = (int*)alloc((size_t)G_ * 4);
    P.pooled = (float*)alloc((size_t)G_ * HDIM * 4);
    P.psc = (float*)alloc(128 * 4);
    P.psh = (float*)alloc(128 * 4);
    P.out = d_out;
    P.E = E_;
    P.N = N_;
    P.G = G_;
    P.NB = NB;
    P.ntiles = ntiles;
    P.TILE = TILE;
    P.invn = 1.f / (float)N_;

    const int oLB1 = oB + 1408;
    const int oLW1 = oLB1 + 128;
    const int oLW2 = oLW1 + 16384;
    const int oLB2 = oLW2 + 1280;
    const int srcIdx[15] = {4, 5, 6, 8, 9, 10, 12, 13, 14, 15, 16, 18, 17, 19, 20};
    const int dstOff[15] = {oB + 0, oB + 128, oB + 256,
                            oB + 384, oB + 512, oB + 640,
                            oB + 768, oB + 896, oB + 1024,
                            oB + 1152, oB + 1280,
                            oLB1, oLW1, oLW2, oLB2};
    for (int i = 0; i < 15; i++) {
        P.tab.p[i] = d_in[srcIdx[i]];
        P.tab.n[i] = in_sizes[srcIdx[i]];
        P.tab.off[i] = dstOff[i];
    }

    mega<<<GRID, 256, 0, stream>>>(P);
}

// Round 10
// 824.681 us; speedup vs baseline: 2.0700x; 2.0700x over previous
//
#include <hip/hip_runtime.h>
#include <hip/hip_bf16.h>
#include <cstdint>

#define HDIM 128

typedef __bf16 bf16x8 __attribute__((ext_vector_type(8)));
typedef unsigned short usx8 __attribute__((ext_vector_type(8)));
typedef float fx4 __attribute__((ext_vector_type(4)));

__device__ __forceinline__ float bf2f(unsigned short u) {
    unsigned int x = ((unsigned int)u) << 16;
    return __uint_as_float(x);
}
__device__ __forceinline__ unsigned short f2bf(float f) {
    unsigned int x = __float_as_uint(f);
    x += 0x7fffu + ((x >> 16) & 1u);
    return (unsigned short)(x >> 16);
}

__device__ __forceinline__ void detect_local(const unsigned int* xw, const unsigned int* eiw,
                                             int& f0, int& f1) {
    int sane = 0;
    for (int k = 0; k < 64; k++) {
        unsigned int w = xw[k];
        unsigned short ss[2] = {(unsigned short)(w & 0xffffu), (unsigned short)(w >> 16)};
        for (int q = 0; q < 2; q++) {
            int e = (ss[q] >> 7) & 0xFF;
            if ((ss[q] & 0x7fffu) == 0 || (e >= 100 && e <= 140)) sane++;
        }
    }
    f0 = (sane >= 110) ? 1 : 0;
    int zeros = 0;
    for (int k = 1; k < 64; k += 2)
        if (eiw[k] == 0) zeros++;
    f1 = (zeros >= 24) ? 1 : 0;
}

struct ParamTab {
    const void* p[15];
    int n[15];
    int off[15];
};

// ---------------- phase1: hist + param-convert + gbounds + repack + init ----------------
__global__ void phase1(const unsigned int* __restrict__ xw, const unsigned int* __restrict__ eiw,
                       const void* __restrict__ ei, const void* __restrict__ batch,
                       const void* __restrict__ W1, const void* __restrict__ W2,
                       const void* __restrict__ W3, ParamTab tab, int* __restrict__ flags,
                       float* __restrict__ gsumAll, int* __restrict__ Ct,
                       unsigned short* __restrict__ wconv, unsigned short* __restrict__ Wf,
                       int* __restrict__ goff, int* __restrict__ gcnt, int E, int N, int G,
                       int NB, int ntiles, int TILE) {
    __shared__ int h[1024];
    __shared__ int lf0s, lf1s;
    int b = blockIdx.x, t = threadIdx.x;
    if (t == 0) {
        int a0, a1;
        detect_local(xw, eiw, a0, a1);
        lf0s = a0;
        lf1s = a1;
    }
    __syncthreads();
    int lf0 = lf0s, lf1 = lf1s;
    if (b < ntiles) {
        for (int i = t; i < NB; i += 256) h[i] = 0;
        __syncthreads();
        int base = b * TILE;
        for (int i = t; i < TILE; i += 256) {
            int idx = base + i;
            if (idx < E) {
                int d = lf1 ? ((const int*)ei)[2 * ((size_t)E + idx)]
                            : ((const int*)ei)[(size_t)E + idx];
                atomicAdd(&h[d >> 9], 1);
            }
        }
        __syncthreads();
        for (int k = t; k < NB; k += 256) Ct[k * ntiles + b] = h[k];
    } else if (b < ntiles + 15) {
        int pb = b - ntiles;
        const void* src = tab.p[pb];
        int n = tab.n[pb];
        unsigned short* o = wconv + tab.off[pb];
        if (lf0) {
            const unsigned short* s = (const unsigned short*)src;
            for (int i = t; i < n; i += 256) o[i] = s[i];
        } else {
            const float* s = (const float*)src;
            for (int i = t; i < n; i += 256) o[i] = f2bf(s[i]);
        }
    } else if (b < ntiles + 17) {
        int gi = (b - ntiles - 15) * 256 + t;
        if (gi < G) {
            auto getb = [&](int i) -> int {
                return lf1 ? (int)((const long long*)batch)[i] : ((const int*)batch)[i];
            };
            auto lower = [&](int val) -> int {
                int lo = 0, hi = N;
                while (lo < hi) {
                    int mid = (lo + hi) >> 1;
                    if (getb(mid) < val) lo = mid + 1;
                    else hi = mid;
                }
                return lo;
            };
            int lo = lower(gi), hi = lower(gi + 1);
            goff[gi] = lo;
            gcnt[gi] = hi - lo;
        }
    } else if (b < ntiles + 41) {
        int idx = (b - ntiles - 17) * 256 + t;  // 0..6143
        int layer = idx >> 11;
        int rem = idx & 2047;
        int kt = rem >> 9, nt = (rem >> 6) & 7, lane = rem & 63;
        const void* W = (layer == 0) ? W1 : ((layer == 1) ? W2 : W3);
        int row = lane & 15, quad = lane >> 4;
        unsigned short* o =
            Wf + ((size_t)layer * 2048 + (size_t)((kt * 8 + nt) * 64 + lane)) * 8;
#pragma unroll
        for (int j = 0; j < 8; j++) {
            int k = kt * 32 + quad * 8 + j;
            int off = k * HDIM + nt * 16 + row;
            o[j] = lf0 ? ((const unsigned short*)W)[off] : f2bf(((const float*)W)[off]);
        }
    } else {
        for (int i = t; i < 6144; i += 256) gsumAll[i] = 0.f;
        if (t == 0) {
            flags[0] = lf0;
            flags[1] = lf1;
        }
    }
}

// ---------------- per-bucket scan over its tile counts (512 threads; ntiles<=512) ---------
__global__ void s1_scan(int* __restrict__ Ct, int* __restrict__ btot, int NB, int ntiles) {
    __shared__ int buf[512];
    int b = blockIdx.x, t = threadIdx.x;
    int v = (t < ntiles) ? Ct[b * ntiles + t] : 0;
    buf[t] = v;
    __syncthreads();
    for (int o = 1; o < 512; o <<= 1) {
        int a = (t >= o) ? buf[t - o] : 0;
        __syncthreads();
        buf[t] += a;
        __syncthreads();
    }
    if (t < ntiles) Ct[b * ntiles + t] = buf[t] - v;  // exclusive within bucket
    if (t == 0) btot[b] = buf[511];
}

// ---------------- scatter to bucket-contiguous packed pairs ----------------
__global__ void p1_scatter(const void* __restrict__ ei, const int* __restrict__ flags,
                           const int* __restrict__ Ct, const int* __restrict__ btot,
                           unsigned int* __restrict__ pairs, int E, int NB, int ntiles,
                           int TILE) {
    __shared__ int cur[1024];
    __shared__ int bb[256];
    int tile = blockIdx.x, t = threadIdx.x;
    int v = (t < NB) ? btot[t] : 0;
    bb[t] = v;
    __syncthreads();
    for (int o = 1; o < 256; o <<= 1) {
        int a = (t >= o) ? bb[t - o] : 0;
        __syncthreads();
        bb[t] += a;
        __syncthreads();
    }
    if (t < NB) cur[t] = (bb[t] - v) + Ct[t * ntiles + tile];
    __syncthreads();
    int base = tile * TILE;
    bool i64 = flags[1] != 0;
    for (int i = t; i < TILE; i += 256) {
        int idx = base + i;
        if (idx < E) {
            int s, d;
            if (i64) {
                s = ((const int*)ei)[2 * (size_t)idx];
                d = ((const int*)ei)[2 * ((size_t)E + idx)];
            } else {
                s = ((const int*)ei)[idx];
                d = ((const int*)ei)[(size_t)E + idx];
            }
            int pos = atomicAdd(&cur[d >> 9], 1);
            pairs[pos] = ((unsigned)(d & 511) << 23) | (unsigned)s;
        }
    }
}

// ---------------- per-bucket: group by node, emit csrc/offs/cnt/dis ----------------
__global__ void p2_build(const unsigned int* __restrict__ pairs, const int* __restrict__ btot,
                         int* __restrict__ csrc, int* __restrict__ offs, int* __restrict__ cnt,
                         float* __restrict__ dis, int E, int N, int NB) {
    __shared__ int hist[512];
    __shared__ int start[512];
    __shared__ int cur[512];
    __shared__ int ps[256];
    __shared__ int bb[256];
    int b = blockIdx.x, t = threadIdx.x;
    int node0 = b * 512;
    int v = (t < NB) ? btot[t] : 0;
    bb[t] = v;
    __syncthreads();
    for (int o = 1; o < 256; o <<= 1) {
        int a = (t >= o) ? bb[t - o] : 0;
        __syncthreads();
        bb[t] += a;
        __syncthreads();
    }
    int lo = bb[b] - btot[b];
    int hi = lo + btot[b];
    for (int i = t; i < 512; i += 256) hist[i] = 0;
    __syncthreads();
    for (int i = lo + t; i < hi; i += 256) atomicAdd(&hist[pairs[i] >> 23], 1);
    __syncthreads();
    ps[t] = hist[2 * t] + hist[2 * t + 1];
    __syncthreads();
    for (int o = 1; o < 256; o <<= 1) {
        int a = (t >= o) ? ps[t - o] : 0;
        __syncthreads();
        ps[t] += a;
        __syncthreads();
    }
    int e = t ? ps[t - 1] : 0;
    start[2 * t] = e;
    start[2 * t + 1] = e + hist[2 * t];
    __syncthreads();
    for (int i = t; i < 512; i += 256) {
        cur[i] = 0;
        int node = node0 + i;
        if (node < N) {
            offs[node] = lo + start[i];
            cnt[node] = hist[i];
            dis[node] = rsqrtf((float)(hist[i] + 1));
        }
    }
    __syncthreads();
    for (int i = lo + t; i < hi; i += 256) {
        unsigned int p = pairs[i];
        int l = p >> 23;
        int pos = lo + start[l] + atomicAdd(&cur[l], 1);
        csrc[pos] = (int)(p & 0x7fffffu);
    }
}

// ---------------- GEMM: hw[slice][m][16] = dis[m] * (bnrelu(A)[m,:] @ W), bf16 MFMA --------
// output column-blocked: slice s holds cols [16s,16s+16)
__global__ __launch_bounds__(256) void mm_mfma(const void* __restrict__ A,
                                               const unsigned short* __restrict__ Wf,
                                               unsigned short* __restrict__ C, int M,
                                               const float* __restrict__ gsumPrev,
                                               const unsigned short* __restrict__ gamma,
                                               const unsigned short* __restrict__ beta,
                                               const float* __restrict__ dis,
                                               const int* __restrict__ flags, int l0mode,
                                               float invn) {
    __shared__ float scs[128], shs[128];
    __shared__ unsigned short ldsC[4 * 16 * 136];
    int t = threadIdx.x;
    if (!l0mode && t < 128) {
        float s = 0.f, s2 = 0.f;
#pragma unroll
        for (int r = 0; r < 8; r++) {
            s += gsumPrev[r * 256 + t];
            s2 += gsumPrev[r * 256 + 128 + t];
        }
        float m = s * invn;
        float vv = s2 * invn - m * m;
        float sc = bf2f(gamma[t]) * rsqrtf(vv + 1e-5f);
        scs[t] = sc;
        shs[t] = bf2f(beta[t]) - m * sc;
    }
    __syncthreads();
    int gid = blockIdx.x * blockDim.x + t;
    int wave = gid >> 6;
    int lane = t & 63;
    int wv = t >> 6;
    int m0 = wave * 16;
    if (m0 >= M) return;
    int row = lane & 15, quad = lane >> 4;
    bool xfp32 = l0mode && !flags[0];
    const unsigned short* arow = (const unsigned short*)A + (size_t)(m0 + row) * HDIM + quad * 8;
    const float* arowf = (const float*)A + (size_t)(m0 + row) * HDIM + quad * 8;
    fx4 acc[8];
#pragma unroll
    for (int k = 0; k < 8; k++) acc[k] = (fx4){0.f, 0.f, 0.f, 0.f};
#pragma unroll
    for (int kt = 0; kt < 4; kt++) {
        bf16x8 a;
        if (xfp32) {
            fx4 f0 = *(const fx4*)(arowf + kt * 32);
            fx4 f1 = *(const fx4*)(arowf + kt * 32 + 4);
            usx8 tt;
#pragma unroll
            for (int q = 0; q < 4; q++) tt[q] = f2bf(f0[q]);
#pragma unroll
            for (int q = 0; q < 4; q++) tt[4 + q] = f2bf(f1[q]);
            a = __builtin_bit_cast(bf16x8, tt);
        } else {
            usx8 raw = *(const usx8*)(arow + kt * 32);
            if (!l0mode) {
                int col = kt * 32 + quad * 8;
                fx4 s0 = *(const fx4*)&scs[col];
                fx4 s1 = *(const fx4*)&scs[col + 4];
                fx4 h0 = *(const fx4*)&shs[col];
                fx4 h1 = *(const fx4*)&shs[col + 4];
                usx8 tt;
#pragma unroll
                for (int q = 0; q < 4; q++)
                    tt[q] = f2bf(fmaxf(s0[q] * bf2f(raw[q]) + h0[q], 0.f));
#pragma unroll
                for (int q = 0; q < 4; q++)
                    tt[4 + q] = f2bf(fmaxf(s1[q] * bf2f(raw[4 + q]) + h1[q], 0.f));
                a = __builtin_bit_cast(bf16x8, tt);
            } else {
                a = __builtin_bit_cast(bf16x8, raw);
            }
        }
        const unsigned short* wf = Wf + ((size_t)(kt * 8) * 64 + lane) * 8;
#pragma unroll
        for (int nt = 0; nt < 8; nt++) {
            bf16x8 bfr = __builtin_bit_cast(bf16x8, *(const usx8*)(wf + (size_t)nt * 64 * 8));
            acc[nt] = __builtin_amdgcn_mfma_f32_16x16x32_bf16(a, bfr, acc[nt], 0, 0, 0);
        }
    }
    float dsc[4];
#pragma unroll
    for (int r = 0; r < 4; r++) dsc[r] = dis[m0 + quad * 4 + r];
    // transpose through per-wave LDS region (stride 136 shorts)
    unsigned short* lw = ldsC + wv * 16 * 136;
#pragma unroll
    for (int nt = 0; nt < 8; nt++) {
        int col = nt * 16 + row;
#pragma unroll
        for (int r = 0; r < 4; r++) {
            lw[(quad * 4 + r) * 136 + col] = f2bf(acc[nt][r] * dsc[r]);
        }
    }
    // readback: column-blocked write. lane -> row16 = lane&15, slice group = lane>>4 (2 slices)
    int row16 = lane & 15;
    int sgrp = lane >> 4;
#pragma unroll
    for (int k = 0; k < 2; k++) {
        int s = sgrp * 2 + k;
        const unsigned short* src = lw + row16 * 136 + s * 16;
        unsigned short* dst = C + (size_t)s * M * 16 + (size_t)(m0 + row16) * 16;
        *(usx8*)(dst) = *(const usx8*)(src);
        *(usx8*)(dst + 8) = *(const usx8*)(src + 8);
    }
}

// ---------------- aggregation: slice-per-block (b&7), 8 nodes/wave, fused BN stats ---------
__global__ __launch_bounds__(256) void aggregate(const unsigned short* __restrict__ hw,
                                                 const float* __restrict__ dis,
                                                 const int* __restrict__ offs,
                                                 const int* __restrict__ cnt,
                                                 const int* __restrict__ csrc,
                                                 const unsigned short* __restrict__ bias,
                                                 unsigned short* __restrict__ agg,
                                                 float* __restrict__ gsum8, int n) {
    __shared__ float red[256];
    int t = threadIdx.x;
    int lane = t & 63;
    int wv = t >> 6;
    int slice = blockIdx.x & 7;
    int bs = blockIdx.x >> 3;
    int nsb = gridDim.x >> 3;
    int ngrp = lane >> 3;  // node group within wave (0..7)
    int cl = lane & 7;     // col pair within slice: cols 2cl, 2cl+1
    const unsigned short* hws = hw + (size_t)slice * n * 16;
    float b0 = bf2f(bias[slice * 16 + 2 * cl]);
    float b1 = bf2f(bias[slice * 16 + 2 * cl + 1]);
    float csum0 = 0.f, csq0 = 0.f, csum1 = 0.f, csq1 = 0.f;
    int stride = nsb * 32;
    for (int node = bs * 32 + wv * 8 + ngrp; node < n; node += stride) {
        unsigned int sv = *(const unsigned int*)(hws + (size_t)node * 16 + 2 * cl);
        float a0 = __uint_as_float(sv << 16);
        float a1 = __uint_as_float(sv & 0xffff0000u);
        int o = offs[node], c = cnt[node];
        int s0 = (c > 0) ? csrc[o] : 0;
        int s1 = (c > 1) ? csrc[o + 1] : 0;
        int s2 = (c > 2) ? csrc[o + 2] : 0;
        int s3 = (c > 3) ? csrc[o + 3] : 0;
        int j = 0;
        while (j < c) {
            unsigned int v0 = *(const unsigned int*)(hws + (size_t)s0 * 16 + 2 * cl);
            unsigned int v1 = *(const unsigned int*)(hws + (size_t)s1 * 16 + 2 * cl);
            unsigned int v2 = *(const unsigned int*)(hws + (size_t)s2 * 16 + 2 * cl);
            unsigned int v3 = *(const unsigned int*)(hws + (size_t)s3 * 16 + 2 * cl);
            s0 = (j + 4 < c) ? csrc[o + j + 4] : 0;
            s1 = (j + 5 < c) ? csrc[o + j + 5] : 0;
            s2 = (j + 6 < c) ? csrc[o + j + 6] : 0;
            s3 = (j + 7 < c) ? csrc[o + j + 7] : 0;
            a0 += __uint_as_float(v0 << 16);
            a1 += __uint_as_float(v0 & 0xffff0000u);
            if (j + 1 < c) {
                a0 += __uint_as_float(v1 << 16);
                a1 += __uint_as_float(v1 & 0xffff0000u);
            }
            if (j + 2 < c) {
                a0 += __uint_as_float(v2 << 16);
                a1 += __uint_as_float(v2 & 0xffff0000u);
            }
            if (j + 3 < c) {
                a0 += __uint_as_float(v3 << 16);
                a1 += __uint_as_float(v3 & 0xffff0000u);
            }
            j += 4;
        }
        float di = dis[node];
        unsigned short o0 = f2bf(b0 + di * a0);
        unsigned short o1 = f2bf(b1 + di * a1);
        float r0 = bf2f(o0), r1 = bf2f(o1);
        csum0 += r0;
        csq0 += r0 * r0;
        csum1 += r1;
        csq1 += r1 * r1;
        *(unsigned int*)(agg + (size_t)node * HDIM + slice * 16 + 2 * cl) =
            ((unsigned int)o1 << 16) | (unsigned int)o0;
    }
    int rep = (bs & 7) * 256;
    // reduce the 4 per-thread stats; threads with (t&7)==cl hold cols 2cl/2cl+1
    red[t] = csum0;
    __syncthreads();
    if (t < 8) {
        float s = 0.f;
        for (int j = t; j < 256; j += 8) s += red[j];
        atomicAdd(&gsum8[rep + slice * 16 + 2 * t], s);
    }
    __syncthreads();
    red[t] = csum1;
    __syncthreads();
    if (t < 8) {
        float s = 0.f;
        for (int j = t; j < 256; j += 8) s += red[j];
        atomicAdd(&gsum8[rep + slice * 16 + 2 * t + 1], s);
    }
    __syncthreads();
    red[t] = csq0;
    __syncthreads();
    if (t < 8) {
        float s = 0.f;
        for (int j = t; j < 256; j += 8) s += red[j];
        atomicAdd(&gsum8[rep + 128 + slice * 16 + 2 * t], s);
    }
    __syncthreads();
    red[t] = csq1;
    __syncthreads();
    if (t < 8) {
        float s = 0.f;
        for (int j = t; j < 256; j += 8) s += red[j];
        atomicAdd(&gsum8[rep + 128 + slice * 16 + 2 * t + 1], s);
    }
}

// ---------------- pooling (computes BN3 in-block, fused ReLU) ----------------
__global__ void pool(const unsigned short* __restrict__ hin, const int* __restrict__ goff,
                     const int* __restrict__ gcnt, const float* __restrict__ gsum3,
                     const unsigned short* __restrict__ gamma,
                     const unsigned short* __restrict__ beta, float* __restrict__ pooled,
                     float invn) {
    __shared__ float scs[128], shs[128];
    __shared__ float ls[256];
    int g = blockIdx.x, t = threadIdx.x;
    if (t < 128) {
        float s = 0.f, s2 = 0.f;
#pragma unroll
        for (int r = 0; r < 8; r++) {
            s += gsum3[r * 256 + t];
            s2 += gsum3[r * 256 + 128 + t];
        }
        float m = s * invn;
        float vv = s2 * invn - m * m;
        float sc = bf2f(gamma[t]) * rsqrtf(vv + 1e-5f);
        scs[t] = sc;
        shs[t] = bf2f(beta[t]) - m * sc;
    }
    __syncthreads();
    int c = t & 127, p = t >> 7;
    float scale = scs[c], shift = shs[c];
    int s = goff[g], cn = gcnt[g];
    float acc = 0.f;
    for (int r = s + p; r < s + cn; r += 2)
        acc += fmaxf(scale * bf2f(hin[(size_t)r * HDIM + c]) + shift, 0.f);
    ls[t] = acc;
    __syncthreads();
    if (t < 128) pooled[(size_t)g * HDIM + t] = (ls[t] + ls[t + 128]) / fmaxf((float)cn, 1.f);
}

// ---------------- fused pooled-BN + MLP head + log_softmax ----------------
__global__ void mlp12(const float* __restrict__ pooled, const unsigned short* __restrict__ gp,
                      const unsigned short* __restrict__ bep,
                      const unsigned short* __restrict__ lw1,
                      const unsigned short* __restrict__ lb1,
                      const unsigned short* __restrict__ lw2,
                      const unsigned short* __restrict__ lb2, void* __restrict__ out,
                      const int* __restrict__ flags, int G_) {
    int r = blockIdx.x, t = threadIdx.x;
    __shared__ float row[128];
    __shared__ float z1s[128];
    __shared__ float z2[10];
    __shared__ float lse;
    // redundant per-block pooled BN stats (pooled is L2-resident, 256 KB)
    float s = 0.f, s2 = 0.f;
    for (int k = 0; k < G_; k++) {
        float v = pooled[(size_t)k * HDIM + t];
        s += v;
        s2 += v * v;
    }
    float m = s / (float)G_;
    float vv = s2 / (float)G_ - m * m;
    float psc = bf2f(gp[t]) * rsqrtf(vv + 1e-5f);
    float psh = bf2f(bep[t]) - m * psc;
    row[t] = psc * pooled[(size_t)r * HDIM + t] + psh;
    __syncthreads();
    float acc = bf2f(lb1[t]);
    for (int k = 0; k < 128; k++) acc += row[k] * bf2f(lw1[k * HDIM + t]);
    z1s[t] = fmaxf(acc, 0.f);
    __syncthreads();
    if (t < 10) {
        float a = bf2f(lb2[t]);
        for (int k = 0; k < 128; k++) a += z1s[k] * bf2f(lw2[k * 10 + t]);
        z2[t] = a;
    }
    __syncthreads();
    if (t == 0) {
        float mm = z2[0];
        for (int j = 1; j < 10; j++) mm = fmaxf(mm, z2[j]);
        float ss = 0.f;
        for (int j = 0; j < 10; j++) ss += expf(z2[j] - mm);
        lse = mm + logf(ss);
    }
    __syncthreads();
    if (t < 10) {
        float v = z2[t] - lse;
        if (flags[0]) ((unsigned short*)out)[r * 10 + t] = f2bf(v);
        else ((float*)out)[r * 10 + t] = v;
    }
}

extern "C" void kernel_launch(void* const* d_in, const int* in_sizes, int n_in,
                              void* d_out, int out_size, void* d_ws, size_t ws_size,
                              hipStream_t stream) {
    const void* x = d_in[0];
    const void* ei = d_in[1];
    const void* batch = d_in[2];

    int N_ = in_sizes[2];
    int E_ = in_sizes[1] / 2;
    int G_ = out_size / 10;

    const int TILE = 4096;      // ntiles <= 512 required by s1_scan
    int NB = (N_ + 511) / 512;  // <= 256 required by in-kernel base scans
    int ntiles = (E_ + TILE - 1) / TILE;
    int L = NB * ntiles;

    char* ws = (char*)d_ws;
    auto alloc = [&](size_t bytes) -> char* {
        char* p = ws;
        ws += (bytes + 255) & ~(size_t)255;
        return p;
    };
    int* flags = (int*)alloc(256);
    float* dis = (float*)alloc((size_t)N_ * 4);
    int* offs = (int*)alloc((size_t)N_ * 4);
    int* cnt = (int*)alloc((size_t)N_ * 4);
    int* Ct = (int*)alloc((size_t)L * 4);
    int* btot = (int*)alloc(1024);
    unsigned int* pairs = (unsigned int*)alloc((size_t)E_ * 4);
    int* csrc = (int*)alloc((size_t)E_ * 4);
    unsigned short* hw = (unsigned short*)alloc((size_t)N_ * HDIM * 2);   // column-blocked
    unsigned short* aggbuf = (unsigned short*)alloc((size_t)N_ * HDIM * 2);  // row-major
    unsigned short* wconv = (unsigned short*)alloc(70000 * 2);
    unsigned short* wfrag = (unsigned short*)alloc(3 * HDIM * HDIM * 2);
    float* gsumAll = (float*)alloc(6144 * 4);
    int* gcnt = (int*)alloc((size_t)G_ * 4);
    int* goff = (int*)alloc((size_t)G_ * 4);
    float* pooled = (float*)alloc((size_t)G_ * HDIM * 4);

    const int oB = 49152;
    const int oLB1 = oB + 1408;
    const int oLW1 = oLB1 + 128;
    const int oLW2 = oLW1 + 16384;
    const int oLB2 = oLW2 + 1280;

    ParamTab tab;
    const int srcIdx[15] = {4, 5, 6, 8, 9, 10, 12, 13, 14, 15, 16, 18, 17, 19, 20};
    const int dstOff[15] = {oB + 0, oB + 128, oB + 256,
                            oB + 384, oB + 512, oB + 640,
                            oB + 768, oB + 896, oB + 1024,
                            oB + 1152, oB + 1280,
                            oLB1, oLW1, oLW2, oLB2};
    for (int i = 0; i < 15; i++) {
        tab.p[i] = d_in[srcIdx[i]];
        tab.n[i] = in_sizes[srcIdx[i]];
        tab.off[i] = dstOff[i];
    }

    int p1_grid = ntiles + 15 + 2 + 24 + 1;
    phase1<<<p1_grid, 256, 0, stream>>>((const unsigned int*)x, (const unsigned int*)ei, ei,
                                        batch, d_in[3], d_in[7], d_in[11], tab, flags, gsumAll,
                                        Ct, wconv, wfrag, goff, gcnt, E_, N_, G_, NB, ntiles,
                                        TILE);
    s1_scan<<<NB, 512, 0, stream>>>(Ct, btot, NB, ntiles);
    p1_scatter<<<ntiles, 256, 0, stream>>>(ei, flags, Ct, btot, pairs, E_, NB, ntiles, TILE);
    p2_build<<<NB, 256, 0, stream>>>(pairs, btot, csrc, offs, cnt, dis, E_, N_, NB);

    int mm_blocks = (((N_ + 15) / 16) * 64 + 255) / 256;
    float invn = 1.f / (float)N_;

    for (int l = 0; l < 3; l++) {
        const void* A = (l == 0) ? x : (const void*)aggbuf;
        const float* gp = (l == 0) ? nullptr : (gsumAll + (size_t)(l - 1) * 2048);
        const unsigned short* gam = wconv + oB + (l ? (l - 1) * 384 + 128 : 0);
        const unsigned short* bet = wconv + oB + (l ? (l - 1) * 384 + 256 : 0);
        mm_mfma<<<mm_blocks, 256, 0, stream>>>(A, wfrag + (size_t)l * HDIM * HDIM, hw, N_, gp,
                                               gam, bet, dis, flags, (l == 0) ? 1 : 0, invn);
        aggregate<<<768, 256, 0, stream>>>(hw, dis, offs, cnt, csrc, wconv + oB + l * 384,
                                           aggbuf, gsumAll + (size_t)l * 2048, N_);
    }

    pool<<<G_, 256, 0, stream>>>(aggbuf, goff, gcnt, gsumAll + 2 * 2048,
                                 wconv + oB + 2 * 384 + 128, wconv + oB + 2 * 384 + 256, pooled,
                                 invn);
    mlp12<<<G_, 128, 0, stream>>>(pooled, wconv + oB + 1152, wconv + oB + 1280, wconv + oLW1,
                                  wconv + oLB1, wconv + oLW2, wconv + oLB2, d_out, flags, G_);
}

// Round 11
// 701.789 us; speedup vs baseline: 2.4325x; 1.1751x over previous
//
#include <hip/hip_runtime.h>
#include <hip/hip_bf16.h>
#include <cstdint>

#define HDIM 128

typedef __bf16 bf16x8 __attribute__((ext_vector_type(8)));
typedef unsigned short usx8 __attribute__((ext_vector_type(8)));
typedef float fx4 __attribute__((ext_vector_type(4)));

__device__ __forceinline__ float bf2f(unsigned short u) {
    unsigned int x = ((unsigned int)u) << 16;
    return __uint_as_float(x);
}
__device__ __forceinline__ unsigned short f2bf(float f) {
    unsigned int x = __float_as_uint(f);
    x += 0x7fffu + ((x >> 16) & 1u);
    return (unsigned short)(x >> 16);
}

__device__ __forceinline__ void detect_local(const unsigned int* xw, const unsigned int* eiw,
                                             int& f0, int& f1) {
    int sane = 0;
    for (int k = 0; k < 64; k++) {
        unsigned int w = xw[k];
        unsigned short ss[2] = {(unsigned short)(w & 0xffffu), (unsigned short)(w >> 16)};
        for (int q = 0; q < 2; q++) {
            int e = (ss[q] >> 7) & 0xFF;
            if ((ss[q] & 0x7fffu) == 0 || (e >= 100 && e <= 140)) sane++;
        }
    }
    f0 = (sane >= 110) ? 1 : 0;
    int zeros = 0;
    for (int k = 1; k < 64; k += 2)
        if (eiw[k] == 0) zeros++;
    f1 = (zeros >= 24) ? 1 : 0;
}

struct ParamTab {
    const void* p[15];
    int n[15];
    int off[15];
};

// ---------------- phase1: hist + param-convert + gbounds + repack + init ----------------
__global__ void phase1(const unsigned int* __restrict__ xw, const unsigned int* __restrict__ eiw,
                       const void* __restrict__ ei, const void* __restrict__ batch,
                       const void* __restrict__ W1, const void* __restrict__ W2,
                       const void* __restrict__ W3, ParamTab tab, int* __restrict__ flags,
                       float* __restrict__ gsumAll, int* __restrict__ Ct,
                       unsigned short* __restrict__ wconv, unsigned short* __restrict__ Wf,
                       int* __restrict__ goff, int* __restrict__ gcnt, int E, int N, int G,
                       int NB, int ntiles, int TILE) {
    __shared__ int h[1024];
    __shared__ int lf0s, lf1s;
    int b = blockIdx.x, t = threadIdx.x;
    if (t == 0) {
        int a0, a1;
        detect_local(xw, eiw, a0, a1);
        lf0s = a0;
        lf1s = a1;
    }
    __syncthreads();
    int lf0 = lf0s, lf1 = lf1s;
    if (b < ntiles) {
        for (int i = t; i < NB; i += 256) h[i] = 0;
        __syncthreads();
        int base = b * TILE;
        for (int i = t; i < TILE; i += 256) {
            int idx = base + i;
            if (idx < E) {
                int d = lf1 ? ((const int*)ei)[2 * ((size_t)E + idx)]
                            : ((const int*)ei)[(size_t)E + idx];
                atomicAdd(&h[d >> 9], 1);
            }
        }
        __syncthreads();
        for (int k = t; k < NB; k += 256) Ct[k * ntiles + b] = h[k];
    } else if (b < ntiles + 15) {
        int pb = b - ntiles;
        const void* src = tab.p[pb];
        int n = tab.n[pb];
        unsigned short* o = wconv + tab.off[pb];
        if (lf0) {
            const unsigned short* s = (const unsigned short*)src;
            for (int i = t; i < n; i += 256) o[i] = s[i];
        } else {
            const float* s = (const float*)src;
            for (int i = t; i < n; i += 256) o[i] = f2bf(s[i]);
        }
    } else if (b < ntiles + 17) {
        int gi = (b - ntiles - 15) * 256 + t;
        if (gi < G) {
            auto getb = [&](int i) -> int {
                return lf1 ? (int)((const long long*)batch)[i] : ((const int*)batch)[i];
            };
            auto lower = [&](int val) -> int {
                int lo = 0, hi = N;
                while (lo < hi) {
                    int mid = (lo + hi) >> 1;
                    if (getb(mid) < val) lo = mid + 1;
                    else hi = mid;
                }
                return lo;
            };
            int lo = lower(gi), hi = lower(gi + 1);
            goff[gi] = lo;
            gcnt[gi] = hi - lo;
        }
    } else if (b < ntiles + 41) {
        int idx = (b - ntiles - 17) * 256 + t;  // 0..6143
        int layer = idx >> 11;
        int rem = idx & 2047;
        int kt = rem >> 9, nt = (rem >> 6) & 7, lane = rem & 63;
        const void* W = (layer == 0) ? W1 : ((layer == 1) ? W2 : W3);
        int row = lane & 15, quad = lane >> 4;
        unsigned short* o =
            Wf + ((size_t)layer * 2048 + (size_t)((kt * 8 + nt) * 64 + lane)) * 8;
#pragma unroll
        for (int j = 0; j < 8; j++) {
            int k = kt * 32 + quad * 8 + j;
            int off = k * HDIM + nt * 16 + row;
            o[j] = lf0 ? ((const unsigned short*)W)[off] : f2bf(((const float*)W)[off]);
        }
    } else {
        for (int i = t; i < 6144; i += 256) gsumAll[i] = 0.f;
        if (t == 0) {
            flags[0] = lf0;
            flags[1] = lf1;
        }
    }
}

// ---------------- per-bucket scan over its tile counts (512 threads; ntiles<=512) ---------
__global__ void s1_scan(int* __restrict__ Ct, int* __restrict__ btot, int NB, int ntiles) {
    __shared__ int buf[512];
    int b = blockIdx.x, t = threadIdx.x;
    int v = (t < ntiles) ? Ct[b * ntiles + t] : 0;
    buf[t] = v;
    __syncthreads();
    for (int o = 1; o < 512; o <<= 1) {
        int a = (t >= o) ? buf[t - o] : 0;
        __syncthreads();
        buf[t] += a;
        __syncthreads();
    }
    if (t < ntiles) Ct[b * ntiles + t] = buf[t] - v;  // exclusive within bucket
    if (t == 0) btot[b] = buf[511];
}

// ---------------- scatter to bucket-contiguous packed pairs ----------------
__global__ void p1_scatter(const void* __restrict__ ei, const int* __restrict__ flags,
                           const int* __restrict__ Ct, const int* __restrict__ btot,
                           unsigned int* __restrict__ pairs, int E, int NB, int ntiles,
                           int TILE) {
    __shared__ int cur[1024];
    __shared__ int bb[256];
    int tile = blockIdx.x, t = threadIdx.x;
    int v = (t < NB) ? btot[t] : 0;
    bb[t] = v;
    __syncthreads();
    for (int o = 1; o < 256; o <<= 1) {
        int a = (t >= o) ? bb[t - o] : 0;
        __syncthreads();
        bb[t] += a;
        __syncthreads();
    }
    if (t < NB) cur[t] = (bb[t] - v) + Ct[t * ntiles + tile];
    __syncthreads();
    int base = tile * TILE;
    bool i64 = flags[1] != 0;
    for (int i = t; i < TILE; i += 256) {
        int idx = base + i;
        if (idx < E) {
            int s, d;
            if (i64) {
                s = ((const int*)ei)[2 * (size_t)idx];
                d = ((const int*)ei)[2 * ((size_t)E + idx)];
            } else {
                s = ((const int*)ei)[idx];
                d = ((const int*)ei)[(size_t)E + idx];
            }
            int pos = atomicAdd(&cur[d >> 9], 1);
            pairs[pos] = ((unsigned)(d & 511) << 23) | (unsigned)s;
        }
    }
}

// ---------------- per-bucket: group by node, emit csrc/offs/cnt/dis ----------------
__global__ void p2_build(const unsigned int* __restrict__ pairs, const int* __restrict__ btot,
                         int* __restrict__ csrc, int* __restrict__ offs, int* __restrict__ cnt,
                         float* __restrict__ dis, int E, int N, int NB) {
    __shared__ int hist[512];
    __shared__ int start[512];
    __shared__ int cur[512];
    __shared__ int ps[256];
    __shared__ int bb[256];
    int b = blockIdx.x, t = threadIdx.x;
    int node0 = b * 512;
    int v = (t < NB) ? btot[t] : 0;
    bb[t] = v;
    __syncthreads();
    for (int o = 1; o < 256; o <<= 1) {
        int a = (t >= o) ? bb[t - o] : 0;
        __syncthreads();
        bb[t] += a;
        __syncthreads();
    }
    int lo = bb[b] - btot[b];
    int hi = lo + btot[b];
    for (int i = t; i < 512; i += 256) hist[i] = 0;
    __syncthreads();
    for (int i = lo + t; i < hi; i += 256) atomicAdd(&hist[pairs[i] >> 23], 1);
    __syncthreads();
    ps[t] = hist[2 * t] + hist[2 * t + 1];
    __syncthreads();
    for (int o = 1; o < 256; o <<= 1) {
        int a = (t >= o) ? ps[t - o] : 0;
        __syncthreads();
        ps[t] += a;
        __syncthreads();
    }
    int e = t ? ps[t - 1] : 0;
    start[2 * t] = e;
    start[2 * t + 1] = e + hist[2 * t];
    __syncthreads();
    for (int i = t; i < 512; i += 256) {
        cur[i] = 0;
        int node = node0 + i;
        if (node < N) {
            offs[node] = lo + start[i];
            cnt[node] = hist[i];
            dis[node] = rsqrtf((float)(hist[i] + 1));
        }
    }
    __syncthreads();
    for (int i = lo + t; i < hi; i += 256) {
        unsigned int p = pairs[i];
        int l = p >> 23;
        int pos = lo + start[l] + atomicAdd(&cur[l], 1);
        csrc[pos] = (int)(p & 0x7fffffu);
    }
}

// ---------------- GEMM: hw[slice][m][16] = dis[m] * (bnrelu(A)[m,:] @ W), bf16 MFMA --------
// output column-blocked: slice s holds cols [16s,16s+16)
__global__ __launch_bounds__(256) void mm_mfma(const void* __restrict__ A,
                                               const unsigned short* __restrict__ Wf,
                                               unsigned short* __restrict__ C, int M,
                                               const float* __restrict__ gsumPrev,
                                               const unsigned short* __restrict__ gamma,
                                               const unsigned short* __restrict__ beta,
                                               const float* __restrict__ dis,
                                               const int* __restrict__ flags, int l0mode,
                                               float invn) {
    __shared__ float scs[128], shs[128];
    __shared__ unsigned short ldsC[4 * 16 * 136];
    int t = threadIdx.x;
    if (!l0mode && t < 128) {
        float s = 0.f, s2 = 0.f;
#pragma unroll
        for (int r = 0; r < 8; r++) {
            s += gsumPrev[r * 256 + t];
            s2 += gsumPrev[r * 256 + 128 + t];
        }
        float m = s * invn;
        float vv = s2 * invn - m * m;
        float sc = bf2f(gamma[t]) * rsqrtf(vv + 1e-5f);
        scs[t] = sc;
        shs[t] = bf2f(beta[t]) - m * sc;
    }
    __syncthreads();
    int gid = blockIdx.x * blockDim.x + t;
    int wave = gid >> 6;
    int lane = t & 63;
    int wv = t >> 6;
    int m0 = wave * 16;
    if (m0 >= M) return;
    int row = lane & 15, quad = lane >> 4;
    bool xfp32 = l0mode && !flags[0];
    const unsigned short* arow = (const unsigned short*)A + (size_t)(m0 + row) * HDIM + quad * 8;
    const float* arowf = (const float*)A + (size_t)(m0 + row) * HDIM + quad * 8;
    fx4 acc[8];
#pragma unroll
    for (int k = 0; k < 8; k++) acc[k] = (fx4){0.f, 0.f, 0.f, 0.f};
#pragma unroll
    for (int kt = 0; kt < 4; kt++) {
        bf16x8 a;
        if (xfp32) {
            fx4 f0 = *(const fx4*)(arowf + kt * 32);
            fx4 f1 = *(const fx4*)(arowf + kt * 32 + 4);
            usx8 tt;
#pragma unroll
            for (int q = 0; q < 4; q++) tt[q] = f2bf(f0[q]);
#pragma unroll
            for (int q = 0; q < 4; q++) tt[4 + q] = f2bf(f1[q]);
            a = __builtin_bit_cast(bf16x8, tt);
        } else {
            usx8 raw = *(const usx8*)(arow + kt * 32);
            if (!l0mode) {
                int col = kt * 32 + quad * 8;
                fx4 s0 = *(const fx4*)&scs[col];
                fx4 s1 = *(const fx4*)&scs[col + 4];
                fx4 h0 = *(const fx4*)&shs[col];
                fx4 h1 = *(const fx4*)&shs[col + 4];
                usx8 tt;
#pragma unroll
                for (int q = 0; q < 4; q++)
                    tt[q] = f2bf(fmaxf(s0[q] * bf2f(raw[q]) + h0[q], 0.f));
#pragma unroll
                for (int q = 0; q < 4; q++)
                    tt[4 + q] = f2bf(fmaxf(s1[q] * bf2f(raw[4 + q]) + h1[q], 0.f));
                a = __builtin_bit_cast(bf16x8, tt);
            } else {
                a = __builtin_bit_cast(bf16x8, raw);
            }
        }
        const unsigned short* wf = Wf + ((size_t)(kt * 8) * 64 + lane) * 8;
#pragma unroll
        for (int nt = 0; nt < 8; nt++) {
            bf16x8 bfr = __builtin_bit_cast(bf16x8, *(const usx8*)(wf + (size_t)nt * 64 * 8));
            acc[nt] = __builtin_amdgcn_mfma_f32_16x16x32_bf16(a, bfr, acc[nt], 0, 0, 0);
        }
    }
    float dsc[4];
#pragma unroll
    for (int r = 0; r < 4; r++) dsc[r] = dis[m0 + quad * 4 + r];
    // transpose through per-wave LDS region (stride 136 shorts)
    unsigned short* lw = ldsC + wv * 16 * 136;
#pragma unroll
    for (int nt = 0; nt < 8; nt++) {
        int col = nt * 16 + row;
#pragma unroll
        for (int r = 0; r < 4; r++) {
            lw[(quad * 4 + r) * 136 + col] = f2bf(acc[nt][r] * dsc[r]);
        }
    }
    // readback: column-blocked write. lane -> row16 = lane&15, slice group = lane>>4 (2 slices)
    int row16 = lane & 15;
    int sgrp = lane >> 4;
#pragma unroll
    for (int k = 0; k < 2; k++) {
        int s = sgrp * 2 + k;
        const unsigned short* src = lw + row16 * 136 + s * 16;
        unsigned short* dst = C + (size_t)s * M * 16 + (size_t)(m0 + row16) * 16;
        *(usx8*)(dst) = *(const usx8*)(src);
        *(usx8*)(dst + 8) = *(const usx8*)(src + 8);
    }
}

// ---------------- aggregation: slice-per-block (b&7), 32 nodes/wave, 16B/lane gathers -------
__global__ __launch_bounds__(256) void aggregate(const unsigned short* __restrict__ hw,
                                                 const float* __restrict__ dis,
                                                 const int* __restrict__ offs,
                                                 const int* __restrict__ cnt,
                                                 const int* __restrict__ csrc,
                                                 const unsigned short* __restrict__ bias,
                                                 unsigned short* __restrict__ agg,
                                                 float* __restrict__ gsum8, int n) {
    __shared__ float ldsS[256 * 16];     // 16 KB: per-thread 8 sums + 8 sqs
    __shared__ float partials[32 * 4];
    int t = threadIdx.x;
    int lane = t & 63;
    int wv = t >> 6;
    int slice = blockIdx.x & 7;
    int bs = blockIdx.x >> 3;
    int nsb = gridDim.x >> 3;
    int nw = lane >> 1;  // node within wave (0..31)
    int h = lane & 1;    // which 8-col half of the 16-col slice
    const unsigned short* hws = hw + (size_t)slice * n * 16;
    int colb = slice * 16 + h * 8;
    usx8 bv = *(const usx8*)(bias + colb);
    float csum[8], csq[8];
#pragma unroll
    for (int q = 0; q < 8; q++) {
        csum[q] = 0.f;
        csq[q] = 0.f;
    }
    int stride = nsb * 128;
    for (int node = bs * 128 + wv * 32 + nw; node < n; node += stride) {
        usx8 sv = *(const usx8*)(hws + (size_t)node * 16 + h * 8);
        float a[8];
#pragma unroll
        for (int q = 0; q < 8; q++) a[q] = bf2f(sv[q]);
        int o = offs[node], c = cnt[node];
        int s0 = (c > 0) ? csrc[o] : 0;
        int s1 = (c > 1) ? csrc[o + 1] : 0;
        int s2 = (c > 2) ? csrc[o + 2] : 0;
        int s3 = (c > 3) ? csrc[o + 3] : 0;
        int j = 0;
        while (j < c) {
            usx8 v0 = *(const usx8*)(hws + (size_t)s0 * 16 + h * 8);
            usx8 v1 = *(const usx8*)(hws + (size_t)s1 * 16 + h * 8);
            usx8 v2 = *(const usx8*)(hws + (size_t)s2 * 16 + h * 8);
            usx8 v3 = *(const usx8*)(hws + (size_t)s3 * 16 + h * 8);
            s0 = (j + 4 < c) ? csrc[o + j + 4] : 0;
            s1 = (j + 5 < c) ? csrc[o + j + 5] : 0;
            s2 = (j + 6 < c) ? csrc[o + j + 6] : 0;
            s3 = (j + 7 < c) ? csrc[o + j + 7] : 0;
#pragma unroll
            for (int q = 0; q < 8; q++) a[q] += bf2f(v0[q]);
            if (j + 1 < c) {
#pragma unroll
                for (int q = 0; q < 8; q++) a[q] += bf2f(v1[q]);
            }
            if (j + 2 < c) {
#pragma unroll
                for (int q = 0; q < 8; q++) a[q] += bf2f(v2[q]);
            }
            if (j + 3 < c) {
#pragma unroll
                for (int q = 0; q < 8; q++) a[q] += bf2f(v3[q]);
            }
            j += 4;
        }
        float di = dis[node];
        usx8 ov;
#pragma unroll
        for (int q = 0; q < 8; q++) {
            float val = bf2f(bv[q]) + di * a[q];
            ov[q] = f2bf(val);
            float vr = bf2f(ov[q]);
            csum[q] += vr;
            csq[q] += vr * vr;
        }
        *(usx8*)(agg + (size_t)node * HDIM + colb) = ov;
    }
    // ---- stats reduction: dump all per-thread values, 2-stage reduce ----
#pragma unroll
    for (int q = 0; q < 8; q++) {
        ldsS[t * 16 + q] = csum[q];
        ldsS[t * 16 + 8 + q] = csq[q];
    }
    __syncthreads();
    if (t < 128) {
        int tgt = t >> 2;  // 0..31: bit0=h, bits1-3=q, bit4=isq
        int part = t & 3;
        int hh = tgt & 1, qq = (tgt >> 1) & 7, isq = tgt >> 4;
        float s = 0.f;
        for (int k = 0; k < 32; k++) {
            int j = part * 64 + 2 * k + hh;
            s += ldsS[j * 16 + isq * 8 + qq];
        }
        partials[tgt * 4 + part] = s;
    }
    __syncthreads();
    if (t < 32) {
        int hh = t & 1, qq = (t >> 1) & 7, isq = t >> 4;
        float s = partials[t * 4] + partials[t * 4 + 1] + partials[t * 4 + 2] +
                  partials[t * 4 + 3];
        atomicAdd(&gsum8[(bs & 7) * 256 + isq * 128 + slice * 16 + hh * 8 + qq], s);
    }
}

// ---------------- pooling (computes BN3 in-block, fused ReLU) ----------------
__global__ void pool(const unsigned short* __restrict__ hin, const int* __restrict__ goff,
                     const int* __restrict__ gcnt, const float* __restrict__ gsum3,
                     const unsigned short* __restrict__ gamma,
                     const unsigned short* __restrict__ beta, float* __restrict__ pooled,
                     float invn) {
    __shared__ float scs[128], shs[128];
    __shared__ float ls[256];
    int g = blockIdx.x, t = threadIdx.x;
    if (t < 128) {
        float s = 0.f, s2 = 0.f;
#pragma unroll
        for (int r = 0; r < 8; r++) {
            s += gsum3[r * 256 + t];
            s2 += gsum3[r * 256 + 128 + t];
        }
        float m = s * invn;
        float vv = s2 * invn - m * m;
        float sc = bf2f(gamma[t]) * rsqrtf(vv + 1e-5f);
        scs[t] = sc;
        shs[t] = bf2f(beta[t]) - m * sc;
    }
    __syncthreads();
    int c = t & 127, p = t >> 7;
    float scale = scs[c], shift = shs[c];
    int s = goff[g], cn = gcnt[g];
    float acc = 0.f;
    for (int r = s + p; r < s + cn; r += 2)
        acc += fmaxf(scale * bf2f(hin[(size_t)r * HDIM + c]) + shift, 0.f);
    ls[t] = acc;
    __syncthreads();
    if (t < 128) pooled[(size_t)g * HDIM + t] = (ls[t] + ls[t + 128]) / fmaxf((float)cn, 1.f);
}

// ---------------- fused pooled-BN + MLP head + log_softmax ----------------
__global__ void mlp12(const float* __restrict__ pooled, const unsigned short* __restrict__ gp,
                      const unsigned short* __restrict__ bep,
                      const unsigned short* __restrict__ lw1,
                      const unsigned short* __restrict__ lb1,
                      const unsigned short* __restrict__ lw2,
                      const unsigned short* __restrict__ lb2, void* __restrict__ out,
                      const int* __restrict__ flags, int G_) {
    int r = blockIdx.x, t = threadIdx.x;
    __shared__ float row[128];
    __shared__ float z1s[128];
    __shared__ float z2[10];
    __shared__ float lse;
    // redundant per-block pooled BN stats (pooled is L2-resident, 256 KB)
    float s = 0.f, s2 = 0.f;
    for (int k = 0; k < G_; k++) {
        float v = pooled[(size_t)k * HDIM + t];
        s += v;
        s2 += v * v;
    }
    float m = s / (float)G_;
    float vv = s2 / (float)G_ - m * m;
    float psc = bf2f(gp[t]) * rsqrtf(vv + 1e-5f);
    float psh = bf2f(bep[t]) - m * psc;
    row[t] = psc * pooled[(size_t)r * HDIM + t] + psh;
    __syncthreads();
    float acc = bf2f(lb1[t]);
    for (int k = 0; k < 128; k++) acc += row[k] * bf2f(lw1[k * HDIM + t]);
    z1s[t] = fmaxf(acc, 0.f);
    __syncthreads();
    if (t < 10) {
        float a = bf2f(lb2[t]);
        for (int k = 0; k < 128; k++) a += z1s[k] * bf2f(lw2[k * 10 + t]);
        z2[t] = a;
    }
    __syncthreads();
    if (t == 0) {
        float mm = z2[0];
        for (int j = 1; j < 10; j++) mm = fmaxf(mm, z2[j]);
        float ss = 0.f;
        for (int j = 0; j < 10; j++) ss += expf(z2[j] - mm);
        lse = mm + logf(ss);
    }
    __syncthreads();
    if (t < 10) {
        float v = z2[t] - lse;
        if (flags[0]) ((unsigned short*)out)[r * 10 + t] = f2bf(v);
        else ((float*)out)[r * 10 + t] = v;
    }
}

extern "C" void kernel_launch(void* const* d_in, const int* in_sizes, int n_in,
                              void* d_out, int out_size, void* d_ws, size_t ws_size,
                              hipStream_t stream) {
    const void* x = d_in[0];
    const void* ei = d_in[1];
    const void* batch = d_in[2];

    int N_ = in_sizes[2];
    int E_ = in_sizes[1] / 2;
    int G_ = out_size / 10;

    const int TILE = 4096;      // ntiles <= 512 required by s1_scan
    int NB = (N_ + 511) / 512;  // <= 256 required by in-kernel base scans
    int ntiles = (E_ + TILE - 1) / TILE;
    int L = NB * ntiles;

    char* ws = (char*)d_ws;
    auto alloc = [&](size_t bytes) -> char* {
        char* p = ws;
        ws += (bytes + 255) & ~(size_t)255;
        return p;
    };
    int* flags = (int*)alloc(256);
    float* dis = (float*)alloc((size_t)N_ * 4);
    int* offs = (int*)alloc((size_t)N_ * 4);
    int* cnt = (int*)alloc((size_t)N_ * 4);
    int* Ct = (int*)alloc((size_t)L * 4);
    int* btot = (int*)alloc(1024);
    unsigned int* pairs = (unsigned int*)alloc((size_t)E_ * 4);
    int* csrc = (int*)alloc((size_t)E_ * 4);
    unsigned short* hw = (unsigned short*)alloc((size_t)N_ * HDIM * 2);      // column-blocked
    unsigned short* aggbuf = (unsigned short*)alloc((size_t)N_ * HDIM * 2);  // row-major
    unsigned short* wconv = (unsigned short*)alloc(70000 * 2);
    unsigned short* wfrag = (unsigned short*)alloc(3 * HDIM * HDIM * 2);
    float* gsumAll = (float*)alloc(6144 * 4);
    int* gcnt = (int*)alloc((size_t)G_ * 4);
    int* goff = (int*)alloc((size_t)G_ * 4);
    float* pooled = (float*)alloc((size_t)G_ * HDIM * 4);

    const int oB = 49152;
    const int oLB1 = oB + 1408;
    const int oLW1 = oLB1 + 128;
    const int oLW2 = oLW1 + 16384;
    const int oLB2 = oLW2 + 1280;

    ParamTab tab;
    const int srcIdx[15] = {4, 5, 6, 8, 9, 10, 12, 13, 14, 15, 16, 18, 17, 19, 20};
    const int dstOff[15] = {oB + 0, oB + 128, oB + 256,
                            oB + 384, oB + 512, oB + 640,
                            oB + 768, oB + 896, oB + 1024,
                            oB + 1152, oB + 1280,
                            oLB1, oLW1, oLW2, oLB2};
    for (int i = 0; i < 15; i++) {
        tab.p[i] = d_in[srcIdx[i]];
        tab.n[i] = in_sizes[srcIdx[i]];
        tab.off[i] = dstOff[i];
    }

    int p1_grid = ntiles + 15 + 2 + 24 + 1;
    phase1<<<p1_grid, 256, 0, stream>>>((const unsigned int*)x, (const unsigned int*)ei, ei,
                                        batch, d_in[3], d_in[7], d_in[11], tab, flags, gsumAll,
                                        Ct, wconv, wfrag, goff, gcnt, E_, N_, G_, NB, ntiles,
                                        TILE);
    s1_scan<<<NB, 512, 0, stream>>>(Ct, btot, NB, ntiles);
    p1_scatter<<<ntiles, 256, 0, stream>>>(ei, flags, Ct, btot, pairs, E_, NB, ntiles, TILE);
    p2_build<<<NB, 256, 0, stream>>>(pairs, btot, csrc, offs, cnt, dis, E_, N_, NB);

    int mm_blocks = (((N_ + 15) / 16) * 64 + 255) / 256;
    float invn = 1.f / (float)N_;

    for (int l = 0; l < 3; l++) {
        const void* A = (l == 0) ? x : (const void*)aggbuf;
        const float* gp = (l == 0) ? nullptr : (gsumAll + (size_t)(l - 1) * 2048);
        const unsigned short* gam = wconv + oB + (l ? (l - 1) * 384 + 128 : 0);
        const unsigned short* bet = wconv + oB + (l ? (l - 1) * 384 + 256 : 0);
        mm_mfma<<<mm_blocks, 256, 0, stream>>>(A, wfrag + (size_t)l * HDIM * HDIM, hw, N_, gp,
                                               gam, bet, dis, flags, (l == 0) ? 1 : 0, invn);
        aggregate<<<768, 256, 0, stream>>>(hw, dis, offs, cnt, csrc, wconv + oB + l * 384,
                                           aggbuf, gsumAll + (size_t)l * 2048, N_);
    }

    pool<<<G_, 256, 0, stream>>>(aggbuf, goff, gcnt, gsumAll + 2 * 2048,
                                 wconv + oB + 2 * 384 + 128, wconv + oB + 2 * 384 + 256, pooled,
                                 invn);
    mlp12<<<G_, 128, 0, stream>>>(pooled, wconv + oB + 1152, wconv + oB + 1280, wconv + oLW1,
                                  wconv + oLB1, wconv + oLW2, wconv + oLB2, d_out, flags, G_);
}